// Round 20
// baseline (155.742 us; speedup 1.0000x reference)
//
#include <hip/hip_runtime.h>

#define KK 12
#define LL 4096
#define DD 128
#define NN 16
#define RR 8
#define NC 128             // chunks (one per block)
#define LC 32              // chunk length = l-tile per block
#define XST 132            // x-tile / ybuf LDS stride (floats)
#define SDST 44            // x_dbl LDS row stride (floats)
#define XDBL_TILE (LC * SDST)   // 1408 floats per (k,chunk) tile

__device__ __forceinline__ int pos_of(int k, int l) {
    int o = k >> 1;
    int le = (k & 1) ? (4095 - l) : l;
    int t1 = le >> 8, t2 = (le >> 4) & 15, t3 = le & 15;
    switch (o) {
        case 0:  return (t1 << 8) | (t2 << 4) | t3;
        case 1:  return (t1 << 8) | (t3 << 4) | t2;
        case 2:  return (t3 << 8) | (t2 << 4) | t1;
        case 3:  return (t2 << 8) | (t3 << 4) | t1;
        case 4:  return (t2 << 8) | (t1 << 4) | t3;
        default: return (t3 << 8) | (t1 << 4) | t2;
    }
}

// Structured requires A[n] = (n+1)*A0 AND A0 == -1 (true for this problem:
// A_logs = log(1..16)), so that exp(dt*A0) == exp(-dt) == (z>=0?E:1)/(1+E).
__device__ __forceinline__ bool load_A8(const float* __restrict__ A_logs,
                                        int k, int d, int n0, float* A8, float& A0) {
    const float4* ap = (const float4*)(A_logs + ((size_t)(k * DD + d) * NN + n0));
    float4 a0 = ap[0], a1 = ap[1];
    A8[0] = -__expf(a0.x); A8[1] = -__expf(a0.y);
    A8[2] = -__expf(a0.z); A8[3] = -__expf(a0.w);
    A8[4] = -__expf(a1.x); A8[5] = -__expf(a1.y);
    A8[6] = -__expf(a1.z); A8[7] = -__expf(a1.w);
    A0 = -__expf(A_logs[(size_t)(k * DD + d) * NN]);
    bool s = (fabsf(A0 + 1.0f) <= 1e-5f);
    #pragma unroll
    for (int j = 0; j < 8; j++) {
        float m = (float)(n0 + j + 1);
        s = s && (fabsf(A8[j] - m * A0) <= 1e-4f * m * fabsf(A0));
    }
    return s;
}

// ---------------------------------------------------------------------------
// K1 scan body with A/B-register software pipeline: while pair P computes,
// pair P' (2 rows ahead) has its delta-row/b/c/u LDS loads already in flight.
// Manual 2x unroll avoids rotation movs. Hazard-safe: prefetched xs rows are
// always >= 2 ahead of any y-write; last dummy reload's values are unused.
// ---------------------------------------------------------------------------
#define K1_LOADPAIR(P, ROW)                                                   \
    P##r0  = *(const float4*)(sdbl + ((ROW) + half) * SDST);                  \
    P##r1  = *(const float4*)(sdbl + ((ROW) + half) * SDST + 4);              \
    P##b0a = *(const float4*)(&sdbl[(ROW) * SDST + 8 + n0]);                  \
    P##b0b = *(const float4*)(&sdbl[(ROW) * SDST + 12 + n0]);                 \
    P##b1a = *(const float4*)(&sdbl[((ROW) + 1) * SDST + 8 + n0]);            \
    P##b1b = *(const float4*)(&sdbl[((ROW) + 1) * SDST + 12 + n0]);           \
    P##c0a = *(const float4*)(&sdbl[(ROW) * SDST + 24 + n0]);                 \
    P##c0b = *(const float4*)(&sdbl[(ROW) * SDST + 28 + n0]);                 \
    P##c1a = *(const float4*)(&sdbl[((ROW) + 1) * SDST + 24 + n0]);           \
    P##c1b = *(const float4*)(&sdbl[((ROW) + 1) * SDST + 28 + n0]);           \
    P##u0  = xs[(ROW) * XST + d];                                             \
    P##u1  = xs[((ROW) + 1) * XST + d];

#define K1_STEP(I, BA, BB, CA, CB, UU, DT, QP)                                \
    {                                                                         \
        float e0, e1, e2, e3, e4, e5, e6, e7;                                 \
        if constexpr (S) {                                                    \
            float q2 = (QP) * (QP), q4 = q2 * q2, q8 = q4 * q4;               \
            e0 = half ? q8 * (QP) : (QP);                                     \
            e1 = e0 * (QP); e2 = e1 * (QP); e3 = e2 * (QP);                   \
            e4 = e3 * (QP); e5 = e4 * (QP); e6 = e5 * (QP); e7 = e6 * (QP);   \
        } else {                                                              \
            e0 = __expf((DT) * A8[0]); e1 = __expf((DT) * A8[1]);             \
            e2 = __expf((DT) * A8[2]); e3 = __expf((DT) * A8[3]);             \
            e4 = __expf((DT) * A8[4]); e5 = __expf((DT) * A8[5]);             \
            e6 = __expf((DT) * A8[6]); e7 = __expf((DT) * A8[7]);             \
        }                                                                     \
        dsum += (DT);                                                         \
        float tu = (DT) * (UU);                                               \
        hv0 = e0 * hv0 + tu * (BA).x;  hv1 = e1 * hv1 + tu * (BA).y;          \
        hv2 = e2 * hv2 + tu * (BA).z;  hv3 = e3 * hv3 + tu * (BA).w;          \
        hv4 = e4 * hv4 + tu * (BB).x;  hv5 = e5 * hv5 + tu * (BB).y;          \
        hv6 = e6 * hv6 + tu * (BB).z;  hv7 = e7 * hv7 + tu * (BB).w;          \
        float yp = (hv0 * (CA).x + hv1 * (CA).y)                              \
                 + (hv2 * (CA).z + hv3 * (CA).w)                              \
                 + (hv4 * (CB).x + hv5 * (CB).y)                              \
                 + (hv6 * (CB).z + hv7 * (CB).w);                             \
        float yv = yp + __shfl_xor(yp, 1) + Dval * (UU);                      \
        if (!half) xs[(I) * XST + d] = yv;                                    \
    }

#define K1_COMPPAIR(P, ROW)                                                   \
    {                                                                         \
        float z = bz + w0.x * P##r0.x + w0.y * P##r0.y + w0.z * P##r0.z       \
                     + w0.w * P##r0.w + w1.x * P##r1.x + w1.y * P##r1.y       \
                     + w1.z * P##r1.z + w1.w * P##r1.w;                       \
        float E = __expf(-fabsf(z));                                          \
        float opE = 1.0f + E;                                                 \
        float dt = fmaxf(z, 0.0f) + __logf(opE);                              \
        float q = 0.0f;                                                       \
        if constexpr (S)                                                      \
            q = (z >= 0.0f ? E : 1.0f) * __builtin_amdgcn_rcpf(opE);          \
        float dto = __shfl_xor(dt, 1);                                        \
        float qo  = S ? __shfl_xor(q, 1) : 0.0f;                              \
        float dt0 = half ? dto : dt,  dt1 = half ? dt : dto;                  \
        float q0  = half ? qo  : q,   q1  = half ? q  : qo;                   \
        K1_STEP((ROW),     P##b0a, P##b0b, P##c0a, P##c0b, P##u0, dt0, q0)    \
        K1_STEP((ROW) + 1, P##b1a, P##b1b, P##c1a, P##c1b, P##u1, dt1, q1)    \
    }

template<bool S>
__device__ __forceinline__ void scanA_body(
    float* xs, const float* sdbl, int k, int c,
    int d, int half, int n0, const float* A8,
    float4 w0, float4 w1, float bz, float Dval,
    float* __restrict__ S_g, float* __restrict__ dtsum)
{
    float hv0 = 0.f, hv1 = 0.f, hv2 = 0.f, hv3 = 0.f;
    float hv4 = 0.f, hv5 = 0.f, hv6 = 0.f, hv7 = 0.f;
    float dsum = 0.0f;

    float4 Ar0, Ar1, Ab0a, Ab0b, Ab1a, Ab1b, Ac0a, Ac0b, Ac1a, Ac1b;
    float  Au0, Au1;
    float4 Br0, Br1, Bb0a, Bb0b, Bb1a, Bb1b, Bc0a, Bc0b, Bc1a, Bc1b;
    float  Bu0, Bu1;

    K1_LOADPAIR(A, 0)
    #pragma unroll 1
    for (int i4 = 0; i4 < LC; i4 += 4) {
        K1_LOADPAIR(B, i4 + 2)                       // rows i4+2,3 (< LC)
        K1_COMPPAIR(A, i4)
        int nxA = (i4 + 4 < LC) ? (i4 + 4) : 0;      // last: dummy reload
        K1_LOADPAIR(A, nxA)
        K1_COMPPAIR(B, i4 + 2)
    }

    float4* sp = (float4*)(S_g + (((size_t)(k * NC + c) * DD + d) * NN + n0));
    sp[0] = make_float4(hv0, hv1, hv2, hv3);
    sp[1] = make_float4(hv4, hv5, hv6, hv7);
    if (!half) dtsum[(k * NC + c) * DD + d] = dsum;
}

// ---------------------------------------------------------------------------
// K1: proj GEMM + phase A local scan. Block = (k, 32-l chunk), 256 threads.
// Staging/GEMM/spill/stores byte-identical to R18 (verified clean).
// ---------------------------------------------------------------------------
__global__ __launch_bounds__(256, 4) void k1_proj_scanA(
    const float* __restrict__ x, const float* __restrict__ Wp,
    const float* __restrict__ Wdt, const float* __restrict__ bias,
    const float* __restrict__ A_logs, const float* __restrict__ Ds,
    float* __restrict__ S_g, float* __restrict__ dtsum,
    float* __restrict__ oy, float* __restrict__ xdbl)
{
    const int blk = blockIdx.x;
    const int k = blk >> 7;
    const int c = blk & 127;
    const int l0 = c * LC;
    const int t = threadIdx.x;

    __shared__ __align__(16) float xs[LC * XST];    // x-tile [l][d]; y overwrites
    __shared__ __align__(16) float sdbl[LC * SDST]; // x_dbl [l][c]
    __shared__ int pos_s[LC];

    if (t < LC) pos_s[t] = pos_of(k, l0 + t);
    __syncthreads();

    // ---- stage x tile: 4 passes x 8 rows x 32 lanes b128 (coalesced) ----
    {
        int lane32 = t & 31, rowi = t >> 5;
        #pragma unroll
        for (int p = 0; p < 4; p++) {
            int l = p * 8 + rowi;
            float4 v = *(const float4*)(x + (size_t)pos_s[l] * DD + lane32 * 4);
            *(float4*)(&xs[l * XST + lane32 * 4]) = v;
        }
    }
    __syncthreads();

    // ---- projection GEMM: group cg (of 8) computes 5 of 40 channels ----
    {
        int l = t & 31, cg = t >> 5;
        float acc[5];
        #pragma unroll
        for (int j = 0; j < 5; j++) acc[j] = 0.0f;
        const float* wk = Wp + (size_t)(k * 40 + cg * 5) * DD;
        for (int d4 = 0; d4 < DD; d4 += 4) {
            float4 xv = *(const float4*)(&xs[l * XST + d4]);
            #pragma unroll
            for (int j = 0; j < 5; j++) {
                const float* w = wk + j * DD + d4;   // wave-uniform -> s_load
                acc[j] += xv.x * w[0] + xv.y * w[1] + xv.z * w[2] + xv.w * w[3];
            }
        }
        #pragma unroll
        for (int j = 0; j < 5; j++) sdbl[l * SDST + cg * 5 + j] = acc[j];
    }
    __syncthreads();

    // ---- spill x_dbl tile for K3 ----
    {
        const float4* s4 = (const float4*)sdbl;
        float4* g4 = (float4*)(xdbl + (size_t)blk * XDBL_TILE);
        for (int idx = t; idx < XDBL_TILE / 4; idx += 256) g4[idx] = s4[idx];
    }

    // ---- phase A scan: thread = (d, n-half) ----
    const int d = t >> 1, half = t & 1, n0 = half * 8;
    float A8[8], A0;
    bool structured = load_A8(A_logs, k, d, n0, A8, A0);
    const float4* wp4 = (const float4*)(Wdt + (size_t)(k * DD + d) * RR);
    const float4 w0 = wp4[0], w1 = wp4[1];
    const float bz = bias[k * DD + d];
    const float Dval = Ds[k * DD + d];

    if (structured)
        scanA_body<true>(xs, sdbl, k, c, d, half, n0, A8, w0, w1, bz,
                         Dval, S_g, dtsum);
    else
        scanA_body<false>(xs, sdbl, k, c, d, half, n0, A8, w0, w1, bz,
                          Dval, S_g, dtsum);

    // ---- transposed y store (intra-wave pair data; no barrier needed) ----
    {
        float* base = oy + ((size_t)(k * DD + d)) * LL + l0 + half * 16;
        #pragma unroll
        for (int p = 0; p < 4; p++) {
            int j = p * 4;
            float4 v = make_float4(xs[(half * 16 + j + 0) * XST + d],
                                   xs[(half * 16 + j + 1) * XST + d],
                                   xs[(half * 16 + j + 2) * XST + d],
                                   xs[(half * 16 + j + 3) * XST + d]);
            *(float4*)(base + j) = v;
        }
    }
}

// ---------------------------------------------------------------------------
// K2: PARALLEL segmented scan over 128 chunks (R18-proven, ~5 us).
// ---------------------------------------------------------------------------
__global__ __launch_bounds__(256) void k2_combine(
    float* __restrict__ S_g, const float* __restrict__ dtsum,
    const float* __restrict__ A_logs)
{
    const int t = threadIdx.x;
    const int s_l = t & 31;                  // scan-in-block 0..31
    const int g   = t >> 5;                  // segment 0..7
    const int sid = blockIdx.x * 32 + s_l;   // = kk*2048 + rem
    const int kk  = sid >> 11, rem = sid & 2047, dd2 = rem >> 4;
    const float Ac = -__expf(A_logs[sid]);

    __shared__ float lsS[8][32];
    __shared__ float lsW[8][32];

    const int c0 = g * 16;

    float S = 0.0f, W = 1.0f;
    #pragma unroll 4
    for (int i = 0; i < 16; i++) {
        int c = c0 + i;
        size_t base = ((size_t)(kk * NC + c)) * 2048 + rem;
        float s = S_g[base];
        float w = __expf(dtsum[(kk * NC + c) * DD + dd2] * Ac);
        S = s + w * S;
        W = w * W;
    }
    lsS[g][s_l] = S;
    lsW[g][s_l] = W;
    __syncthreads();

    float h = 0.0f;
    for (int j = 0; j < g; j++)
        h = lsS[j][s_l] + lsW[j][s_l] * h;

    #pragma unroll 4
    for (int i = 0; i < 16; i++) {
        int c = c0 + i;
        size_t base = ((size_t)(kk * NC + c)) * 2048 + rem;
        float s = S_g[base];
        float w = __expf(dtsum[(kk * NC + c) * DD + dd2] * Ac);
        S_g[base] = h;
        h = s + w * h;
    }
}

// ---------------------------------------------------------------------------
// K3 body with the same A/B pipeline (delta row + 4x c per pair).
// ---------------------------------------------------------------------------
#define K3_LOADPAIR(P, ROW)                                                   \
    P##r0  = *(const float4*)(sdbl + ((ROW) + half) * SDST);                  \
    P##r1  = *(const float4*)(sdbl + ((ROW) + half) * SDST + 4);              \
    P##c0a = *(const float4*)(&sdbl[(ROW) * SDST + 24 + n0]);                 \
    P##c0b = *(const float4*)(&sdbl[(ROW) * SDST + 28 + n0]);                 \
    P##c1a = *(const float4*)(&sdbl[((ROW) + 1) * SDST + 24 + n0]);           \
    P##c1b = *(const float4*)(&sdbl[((ROW) + 1) * SDST + 28 + n0]);

#define K3_STEP(I, CA, CB, DT, QP)                                            \
    {                                                                         \
        float yp;                                                             \
        if constexpr (S) {                                                    \
            Q *= (QP);                                                        \
            float sH =          h0[7] * (CB).w;                               \
            sH = sH * Q + h0[6] * (CB).z;                                     \
            sH = sH * Q + h0[5] * (CB).y;                                     \
            sH = sH * Q + h0[4] * (CB).x;                                     \
            sH = sH * Q + h0[3] * (CA).w;                                     \
            sH = sH * Q + h0[2] * (CA).z;                                     \
            sH = sH * Q + h0[1] * (CA).y;                                     \
            sH = sH * Q + h0[0] * (CA).x;                                     \
            float Q2 = Q * Q, Q4 = Q2 * Q2, Q8 = Q4 * Q4;                     \
            float Qp = half ? Q8 * Q : Q;                                     \
            yp = sH * Qp;                                                     \
        } else {                                                              \
            Dsum += (DT);                                                     \
            yp = __expf(Dsum * A8[0]) * h0[0] * (CA).x                        \
               + __expf(Dsum * A8[1]) * h0[1] * (CA).y                        \
               + __expf(Dsum * A8[2]) * h0[2] * (CA).z                        \
               + __expf(Dsum * A8[3]) * h0[3] * (CA).w                        \
               + __expf(Dsum * A8[4]) * h0[4] * (CB).x                        \
               + __expf(Dsum * A8[5]) * h0[5] * (CB).y                        \
               + __expf(Dsum * A8[6]) * h0[6] * (CB).z                        \
               + __expf(Dsum * A8[7]) * h0[7] * (CB).w;                       \
        }                                                                     \
        float yv = yp + __shfl_xor(yp, 1);                                    \
        if (!half) ybuf[(I) * XST + d] = yv;                                  \
    }

#define K3_COMPPAIR(P, ROW)                                                   \
    {                                                                         \
        float z = bz + w0.x * P##r0.x + w0.y * P##r0.y + w0.z * P##r0.z       \
                     + w0.w * P##r0.w + w1.x * P##r1.x + w1.y * P##r1.y       \
                     + w1.z * P##r1.z + w1.w * P##r1.w;                       \
        float E = __expf(-fabsf(z));                                          \
        float opE = 1.0f + E;                                                 \
        float dt = fmaxf(z, 0.0f) + __logf(opE);                              \
        float q = 0.0f;                                                      \
        if constexpr (S)                                                      \
            q = (z >= 0.0f ? E : 1.0f) * __builtin_amdgcn_rcpf(opE);          \
        float dto = __shfl_xor(dt, 1);                                        \
        float qo  = S ? __shfl_xor(q, 1) : 0.0f;                              \
        float dt0 = half ? dto : dt,  dt1 = half ? dt : dto;                  \
        float q0  = half ? qo  : q,   q1  = half ? q  : qo;                   \
        K3_STEP((ROW),     P##c0a, P##c0b, dt0, q0)                           \
        K3_STEP((ROW) + 1, P##c1a, P##c1b, dt1, q1)                           \
    }

template<bool S>
__device__ __forceinline__ void corr_body(
    float* ybuf, const float* sdbl, int d, int half, int n0,
    const float* A8, const float* h0, float4 w0, float4 w1, float bz)
{
    float Q = 1.0f;
    float Dsum = 0.0f;

    float4 Ar0, Ar1, Ac0a, Ac0b, Ac1a, Ac1b;
    float4 Br0, Br1, Bc0a, Bc0b, Bc1a, Bc1b;

    K3_LOADPAIR(A, 0)
    #pragma unroll 1
    for (int i4 = 0; i4 < LC; i4 += 4) {
        K3_LOADPAIR(B, i4 + 2)
        K3_COMPPAIR(A, i4)
        int nxA = (i4 + 4 < LC) ? (i4 + 4) : 0;
        K3_LOADPAIR(A, nxA)
        K3_COMPPAIR(B, i4 + 2)
    }
}

__global__ __launch_bounds__(256, 4) void k3_corr(
    const float* __restrict__ Wdt, const float* __restrict__ bias,
    const float* __restrict__ A_logs, const float* __restrict__ S_g,
    const float* __restrict__ xdbl, float* __restrict__ oy)
{
    const int blk = blockIdx.x;
    const int k = blk >> 7;
    const int c = blk & 127;
    if (c == 0) return;                 // chunk 0 has h0 = 0
    const int l0 = c * LC;
    const int t = threadIdx.x;

    __shared__ __align__(16) float sdbl[LC * SDST];
    __shared__ __align__(16) float ybuf[LC * XST];
    {
        const float4* g4 = (const float4*)(xdbl + (size_t)blk * XDBL_TILE);
        float4* s4 = (float4*)sdbl;
        for (int idx = t; idx < XDBL_TILE / 4; idx += 256) s4[idx] = g4[idx];
    }
    __syncthreads();

    const int d = t >> 1, half = t & 1, n0 = half * 8;
    float A8[8], A0;
    bool structured = load_A8(A_logs, k, d, n0, A8, A0);
    const float4* wp4 = (const float4*)(Wdt + (size_t)(k * DD + d) * RR);
    const float4 w0 = wp4[0], w1 = wp4[1];
    const float bz = bias[k * DD + d];

    float h0[8];
    {
        const float4* hp = (const float4*)(S_g + (((size_t)(k * NC + c) * DD + d) * NN + n0));
        float4 h40 = hp[0], h41 = hp[1];
        h0[0] = h40.x; h0[1] = h40.y; h0[2] = h40.z; h0[3] = h40.w;
        h0[4] = h41.x; h0[5] = h41.y; h0[6] = h41.z; h0[7] = h41.w;
    }

    if (structured)
        corr_body<true>(ybuf, sdbl, d, half, n0, A8, h0, w0, w1, bz);
    else
        corr_body<false>(ybuf, sdbl, d, half, n0, A8, h0, w0, w1, bz);

    // ---- transposed RMW of oy tile (intra-wave pair data) ----
    {
        float* base = oy + ((size_t)(k * DD + d)) * LL + l0 + half * 16;
        #pragma unroll
        for (int p = 0; p < 4; p++) {
            int j = p * 4;
            float4 v = *(float4*)(base + j);
            v.x += ybuf[(half * 16 + j + 0) * XST + d];
            v.y += ybuf[(half * 16 + j + 1) * XST + d];
            v.z += ybuf[(half * 16 + j + 2) * XST + d];
            v.w += ybuf[(half * 16 + j + 3) * XST + d];
            *(float4*)(base + j) = v;
        }
    }
}

// ---------------------------------------------------------------------------
// K4: restore + merge (reference's (D,L)-flat reshape semantics), float4.
// ---------------------------------------------------------------------------
__global__ __launch_bounds__(256) void k4_merge(
    const float* __restrict__ out_y, const float* __restrict__ mw,
    const float* __restrict__ mb, float* __restrict__ out)
{
    int idx4 = blockIdx.x * 256 + threadIdx.x;   // float4 index
    int dd4 = (idx4 & 31) * 4;
    int p = idx4 >> 5;
    int i3 = p & 15, i2 = (p >> 4) & 15, i1 = (p >> 8) & 15;

    float b = mb[0];
    float4 accv = make_float4(b, b, b, b);
    #pragma unroll
    for (int k = 0; k < 12; k++) {
        int a1 = i1, a2 = i2, a3 = i3;
        if (k & 1) { a1 = 15 - i1; a2 = 15 - i2; a3 = 15 - i3; }
        int j1, j2, j3;
        switch (k >> 1) {
            case 0:  j1 = a1; j2 = a2; j3 = a3; break;
            case 1:  j1 = a1; j2 = a3; j3 = a2; break;
            case 2:  j1 = a3; j2 = a2; j3 = a1; break;
            case 3:  j1 = a3; j2 = a1; j3 = a2; break;
            case 4:  j1 = a2; j2 = a1; j3 = a3; break;
            default: j1 = a2; j2 = a3; j3 = a1; break;
        }
        int jb = (j1 << 8) | (j2 << 4) | j3;
        float4 v = *(const float4*)(out_y + (size_t)k * (DD * LL) + (jb >> 5) * LL
                                    + ((jb & 31) << 7) + dd4);
        float w = mw[k];
        accv.x += w * v.x; accv.y += w * v.y;
        accv.z += w * v.z; accv.w += w * v.w;
    }
    *(float4*)(out + (size_t)p * DD + dd4) = accv;
}

extern "C" void kernel_launch(void* const* d_in, const int* in_sizes, int n_in,
                              void* d_out, int out_size, void* d_ws, size_t ws_size,
                              hipStream_t stream) {
    const float* x      = (const float*)d_in[0];
    const float* Wp     = (const float*)d_in[1];
    const float* Wdt    = (const float*)d_in[2];
    const float* bias   = (const float*)d_in[3];
    const float* A_logs = (const float*)d_in[4];
    const float* Ds     = (const float*)d_in[5];
    const float* mw     = (const float*)d_in[6];
    const float* mb     = (const float*)d_in[7];
    float* out = (float*)d_out;

    float* ws   = (float*)d_ws;
    float* S_g  = ws;                                 // K*NC*D*N = 1572864
    float* dts  = S_g + (size_t)KK * NC * DD * NN;    // K*NC*D   =   98304
    float* oy   = dts + (size_t)KK * NC * DD;         // K*D*L    = 6291456
    float* xdbl = oy + (size_t)KK * DD * LL;          // 1536*1408 = 2162688

    k1_proj_scanA<<<dim3(KK * NC), dim3(256), 0, stream>>>(
        x, Wp, Wdt, bias, A_logs, Ds, S_g, dts, oy, xdbl);
    k2_combine<<<dim3(KK * DD * NN / 32), dim3(256), 0, stream>>>(S_g, dts, A_logs);
    k3_corr<<<dim3(KK * NC), dim3(256), 0, stream>>>(Wdt, bias, A_logs, S_g, xdbl, oy);
    k4_merge<<<dim3(LL * DD / 1024), dim3(256), 0, stream>>>(oy, mw, mb, out);
}

// Round 21
// 154.643 us; speedup vs baseline: 1.0071x; 1.0071x over previous
//
#include <hip/hip_runtime.h>

#define KK 12
#define LL 4096
#define DD 128
#define NN 16
#define RR 8
#define NC 128             // chunks (one per block)
#define LC 32              // chunk length = l-tile per block
#define XST 132            // x-tile / ybuf LDS stride (floats)
#define SDST 44            // x_dbl LDS row stride (floats)
#define XDBL_TILE (LC * SDST)   // 1408 floats per (k,chunk) tile

__device__ __forceinline__ int pos_of(int k, int l) {
    int o = k >> 1;
    int le = (k & 1) ? (4095 - l) : l;
    int t1 = le >> 8, t2 = (le >> 4) & 15, t3 = le & 15;
    switch (o) {
        case 0:  return (t1 << 8) | (t2 << 4) | t3;
        case 1:  return (t1 << 8) | (t3 << 4) | t2;
        case 2:  return (t3 << 8) | (t2 << 4) | t1;
        case 3:  return (t2 << 8) | (t3 << 4) | t1;
        case 4:  return (t2 << 8) | (t1 << 4) | t3;
        default: return (t3 << 8) | (t1 << 4) | t2;
    }
}

__device__ __forceinline__ float delta_row_z(const float* sdbl, int l,
                                             float4 w0, float4 w1, float bz) {
    const float4* dr = (const float4*)(sdbl + l * SDST);
    float4 r0 = dr[0], r1 = dr[1];
    return bz + w0.x * r0.x + w0.y * r0.y + w0.z * r0.z + w0.w * r0.w
              + w1.x * r1.x + w1.y * r1.y + w1.z * r1.z + w1.w * r1.w;
}

// Structured requires A[n] = (n+1)*A0 AND A0 == -1 (true for this problem:
// A_logs = log(1..16)), so that exp(dt*A0) == exp(-dt) == (z>=0?E:1)/(1+E).
__device__ __forceinline__ bool load_A8(const float* __restrict__ A_logs,
                                        int k, int d, int n0, float* A8, float& A0) {
    const float4* ap = (const float4*)(A_logs + ((size_t)(k * DD + d) * NN + n0));
    float4 a0 = ap[0], a1 = ap[1];
    A8[0] = -__expf(a0.x); A8[1] = -__expf(a0.y);
    A8[2] = -__expf(a0.z); A8[3] = -__expf(a0.w);
    A8[4] = -__expf(a1.x); A8[5] = -__expf(a1.y);
    A8[6] = -__expf(a1.z); A8[7] = -__expf(a1.w);
    A0 = -__expf(A_logs[(size_t)(k * DD + d) * NN]);
    bool s = (fabsf(A0 + 1.0f) <= 1e-5f);
    #pragma unroll
    for (int j = 0; j < 8; j++) {
        float m = (float)(n0 + j + 1);
        s = s && (fabsf(A8[j] - m * A0) <= 1e-4f * m * fabsf(A0));
    }
    return s;
}

// ---------------------------------------------------------------------------
// One scan step. Structured path takes q = exp(-dt) directly (no exp here).
// ---------------------------------------------------------------------------
template<bool S>
__device__ __forceinline__ void scan_step(
    float* xs, const float* sdbl, int i, int d, int half, int n0,
    const float* A8, float dt, float q, float Dval, float* h, float& dsum)
{
    float u = xs[i * XST + d];
    dsum += dt;
    float tu = dt * u;
    float e[8];
    if constexpr (S) {
        float q2 = q * q, q4 = q2 * q2, q8 = q4 * q4;
        e[0] = half ? q8 * q : q;
        #pragma unroll
        for (int j = 1; j < 8; j++) e[j] = e[j - 1] * q;
    } else {
        #pragma unroll
        for (int j = 0; j < 8; j++) e[j] = __expf(dt * A8[j]);
    }
    const float4* bp = (const float4*)(&sdbl[i * SDST + 8 + n0]);
    float4 b0 = bp[0], b1 = bp[1];
    const float4* cp = (const float4*)(&sdbl[i * SDST + 24 + n0]);
    float4 c0 = cp[0], c1 = cp[1];
    h[0] = e[0] * h[0] + tu * b0.x;  h[1] = e[1] * h[1] + tu * b0.y;
    h[2] = e[2] * h[2] + tu * b0.z;  h[3] = e[3] * h[3] + tu * b0.w;
    h[4] = e[4] * h[4] + tu * b1.x;  h[5] = e[5] * h[5] + tu * b1.y;
    h[6] = e[6] * h[6] + tu * b1.z;  h[7] = e[7] * h[7] + tu * b1.w;
    float yp = h[0] * c0.x + h[1] * c0.y + h[2] * c0.z + h[3] * c0.w
             + h[4] * c1.x + h[5] * c1.y + h[6] * c1.z + h[7] * c1.w;
    float yv = yp + __shfl_xor(yp, 1) + Dval * u;
    if (!half) xs[i * XST + d] = yv;
}

// ---------------------------------------------------------------------------
// K1 scan body. Pairwise delta: lane `half` computes Delta for row i+half,
// partner's value arrives via quad-perm shfl_xor — halves z/softplus cost.
// ---------------------------------------------------------------------------
template<bool S>
__device__ __forceinline__ void scanA_body(
    float* xs, const float* sdbl, int k, int c,
    int d, int half, int n0, const float* A8,
    float4 w0, float4 w1, float bz, float Dval,
    float* __restrict__ S_g, float* __restrict__ dtsum)
{
    float h[8] = {0, 0, 0, 0, 0, 0, 0, 0};
    float dsum = 0.0f;

    #pragma unroll 2
    for (int i2 = 0; i2 < LC; i2 += 2) {
        float z = delta_row_z(sdbl, i2 + half, w0, w1, bz);
        float E = __expf(-fabsf(z));
        float opE = 1.0f + E;
        float dt = fmaxf(z, 0.0f) + __logf(opE);
        float q = 0.0f;
        if constexpr (S)
            q = (z >= 0.0f ? E : 1.0f) * __builtin_amdgcn_rcpf(opE);
        float dto = __shfl_xor(dt, 1);
        float qo  = S ? __shfl_xor(q, 1) : 0.0f;
        float dt0 = half ? dto : dt,  dt1 = half ? dt : dto;
        float q0  = half ? qo  : q,   q1  = half ? q  : qo;
        scan_step<S>(xs, sdbl, i2,     d, half, n0, A8, dt0, q0, Dval, h, dsum);
        scan_step<S>(xs, sdbl, i2 + 1, d, half, n0, A8, dt1, q1, Dval, h, dsum);
    }

    float4* sp = (float4*)(S_g + (((size_t)(k * NC + c) * DD + d) * NN + n0));
    sp[0] = make_float4(h[0], h[1], h[2], h[3]);
    sp[1] = make_float4(h[4], h[5], h[6], h[7]);
    if (!half) dtsum[(k * NC + c) * DD + d] = dsum;
}

// ---------------------------------------------------------------------------
// K1: proj GEMM + phase A local scan. Block = (k, 32-l chunk), 256 threads.
// LDS 22.7 KB; (256,4) -> 44 VGPR, no scratch (verified R2/R8/R18 counters).
// ---------------------------------------------------------------------------
__global__ __launch_bounds__(256, 4) void k1_proj_scanA(
    const float* __restrict__ x, const float* __restrict__ Wp,
    const float* __restrict__ Wdt, const float* __restrict__ bias,
    const float* __restrict__ A_logs, const float* __restrict__ Ds,
    float* __restrict__ S_g, float* __restrict__ dtsum,
    float* __restrict__ oy, float* __restrict__ xdbl)
{
    const int blk = blockIdx.x;
    const int k = blk >> 7;
    const int c = blk & 127;
    const int l0 = c * LC;
    const int t = threadIdx.x;

    __shared__ __align__(16) float xs[LC * XST];    // x-tile [l][d]; y overwrites
    __shared__ __align__(16) float sdbl[LC * SDST]; // x_dbl [l][c]
    __shared__ int pos_s[LC];

    if (t < LC) pos_s[t] = pos_of(k, l0 + t);
    __syncthreads();

    // ---- stage x tile: 4 passes x 8 rows x 32 lanes b128 (coalesced) ----
    {
        int lane32 = t & 31, rowi = t >> 5;
        #pragma unroll
        for (int p = 0; p < 4; p++) {
            int l = p * 8 + rowi;
            float4 v = *(const float4*)(x + (size_t)pos_s[l] * DD + lane32 * 4);
            *(float4*)(&xs[l * XST + lane32 * 4]) = v;
        }
    }
    __syncthreads();

    // ---- projection GEMM: group cg (of 8) computes 5 of 40 channels ----
    {
        int l = t & 31, cg = t >> 5;
        float acc[5];
        #pragma unroll
        for (int j = 0; j < 5; j++) acc[j] = 0.0f;
        const float* wk = Wp + (size_t)(k * 40 + cg * 5) * DD;
        for (int d4 = 0; d4 < DD; d4 += 4) {
            float4 xv = *(const float4*)(&xs[l * XST + d4]);
            #pragma unroll
            for (int j = 0; j < 5; j++) {
                const float* w = wk + j * DD + d4;   // wave-uniform -> s_load
                acc[j] += xv.x * w[0] + xv.y * w[1] + xv.z * w[2] + xv.w * w[3];
            }
        }
        #pragma unroll
        for (int j = 0; j < 5; j++) sdbl[l * SDST + cg * 5 + j] = acc[j];
    }
    __syncthreads();

    // ---- spill x_dbl tile for K3 ----
    {
        const float4* s4 = (const float4*)sdbl;
        float4* g4 = (float4*)(xdbl + (size_t)blk * XDBL_TILE);
        for (int idx = t; idx < XDBL_TILE / 4; idx += 256) g4[idx] = s4[idx];
    }

    // ---- phase A scan: thread = (d, n-half) ----
    const int d = t >> 1, half = t & 1, n0 = half * 8;
    float A8[8], A0;
    bool structured = load_A8(A_logs, k, d, n0, A8, A0);
    const float4* wp4 = (const float4*)(Wdt + (size_t)(k * DD + d) * RR);
    const float4 w0 = wp4[0], w1 = wp4[1];
    const float bz = bias[k * DD + d];
    const float Dval = Ds[k * DD + d];

    if (structured)
        scanA_body<true>(xs, sdbl, k, c, d, half, n0, A8, w0, w1, bz,
                         Dval, S_g, dtsum);
    else
        scanA_body<false>(xs, sdbl, k, c, d, half, n0, A8, w0, w1, bz,
                          Dval, S_g, dtsum);

    // ---- transposed y store (intra-wave pair data; no barrier needed) ----
    {
        float* base = oy + ((size_t)(k * DD + d)) * LL + l0 + half * 16;
        #pragma unroll
        for (int p = 0; p < 4; p++) {
            int j = p * 4;
            float4 v = make_float4(xs[(half * 16 + j + 0) * XST + d],
                                   xs[(half * 16 + j + 1) * XST + d],
                                   xs[(half * 16 + j + 2) * XST + d],
                                   xs[(half * 16 + j + 3) * XST + d]);
            *(float4*)(base + j) = v;
        }
    }
}

// ---------------------------------------------------------------------------
// K2: PARALLEL segmented scan over 128 chunks (R18-proven, ~5 us). 8
// segment-threads per scan (16 chunks each): phase 1 composes each segment's
// affine map (S,W) for h -> s + w*h; phase 2 LDS-exchanges and computes
// segment-start h; phase 3 re-walks writing exclusive prefixes into S_g.
// ---------------------------------------------------------------------------
__global__ __launch_bounds__(256) void k2_combine(
    float* __restrict__ S_g, const float* __restrict__ dtsum,
    const float* __restrict__ A_logs)
{
    const int t = threadIdx.x;
    const int s_l = t & 31;                  // scan-in-block 0..31
    const int g   = t >> 5;                  // segment 0..7
    const int sid = blockIdx.x * 32 + s_l;   // = kk*2048 + rem
    const int kk  = sid >> 11, rem = sid & 2047, dd2 = rem >> 4;
    const float Ac = -__expf(A_logs[sid]);

    __shared__ float lsS[8][32];
    __shared__ float lsW[8][32];

    const int c0 = g * 16;

    float S = 0.0f, W = 1.0f;
    #pragma unroll 4
    for (int i = 0; i < 16; i++) {
        int c = c0 + i;
        size_t base = ((size_t)(kk * NC + c)) * 2048 + rem;
        float s = S_g[base];
        float w = __expf(dtsum[(kk * NC + c) * DD + dd2] * Ac);
        S = s + w * S;
        W = w * W;
    }
    lsS[g][s_l] = S;
    lsW[g][s_l] = W;
    __syncthreads();

    float h = 0.0f;
    for (int j = 0; j < g; j++)
        h = lsS[j][s_l] + lsW[j][s_l] * h;

    #pragma unroll 4
    for (int i = 0; i < 16; i++) {
        int c = c0 + i;
        size_t base = ((size_t)(kk * NC + c)) * 2048 + rem;
        float s = S_g[base];
        float w = __expf(dtsum[(kk * NC + c) * DD + dd2] * Ac);
        S_g[base] = h;
        h = s + w * h;
    }
}

// ---------------------------------------------------------------------------
// K3 body: y(l) += C(l) . (exp(Dsum_l * A) (.) h0).
// Structured: running product Q = exp(-Dsum) (one mul per step, no exp/log),
// per-n powers folded into a 7-FMA Horner:  yp = Q^{n0+1} * sum_j g_j Q^j.
// ---------------------------------------------------------------------------
template<bool S>
__device__ __forceinline__ void corr_body(
    float* ybuf, const float* sdbl, int d, int half, int n0,
    const float* A8, const float* h0, float4 w0, float4 w1, float bz)
{
    if constexpr (S) {
        float Q = 1.0f;
        #pragma unroll 2
        for (int i2 = 0; i2 < LC; i2 += 2) {
            float z = delta_row_z(sdbl, i2 + half, w0, w1, bz);
            float E = __expf(-fabsf(z));
            float q = (z >= 0.0f ? E : 1.0f) * __builtin_amdgcn_rcpf(1.0f + E);
            float qo = __shfl_xor(q, 1);
            float q0 = half ? qo : q, q1 = half ? q : qo;
            #pragma unroll
            for (int s = 0; s < 2; s++) {
                int i = i2 + s;
                Q *= (s ? q1 : q0);
                const float4* cp = (const float4*)(&sdbl[i * SDST + 24 + n0]);
                float4 c0 = cp[0], c1 = cp[1];
                float sH =           h0[7] * c1.w;
                sH = sH * Q + h0[6] * c1.z;
                sH = sH * Q + h0[5] * c1.y;
                sH = sH * Q + h0[4] * c1.x;
                sH = sH * Q + h0[3] * c0.w;
                sH = sH * Q + h0[2] * c0.z;
                sH = sH * Q + h0[1] * c0.y;
                sH = sH * Q + h0[0] * c0.x;
                float Q2 = Q * Q, Q4 = Q2 * Q2, Q8 = Q4 * Q4;
                float Qp = half ? Q8 * Q : Q;
                float yp = sH * Qp;
                float yv = yp + __shfl_xor(yp, 1);
                if (!half) ybuf[i * XST + d] = yv;
            }
        }
    } else {
        float Dsum = 0.0f;
        #pragma unroll 2
        for (int i2 = 0; i2 < LC; i2 += 2) {
            float z = delta_row_z(sdbl, i2 + half, w0, w1, bz);
            float E = __expf(-fabsf(z));
            float dt = fmaxf(z, 0.0f) + __logf(1.0f + E);
            float dto = __shfl_xor(dt, 1);
            float dt0 = half ? dto : dt, dt1 = half ? dt : dto;
            #pragma unroll
            for (int s = 0; s < 2; s++) {
                int i = i2 + s;
                Dsum += (s ? dt1 : dt0);
                float e[8];
                #pragma unroll
                for (int j = 0; j < 8; j++) e[j] = __expf(Dsum * A8[j]);
                const float4* cp = (const float4*)(&sdbl[i * SDST + 24 + n0]);
                float4 c0 = cp[0], c1 = cp[1];
                float yp = e[0]*h0[0]*c0.x + e[1]*h0[1]*c0.y + e[2]*h0[2]*c0.z + e[3]*h0[3]*c0.w
                         + e[4]*h0[4]*c1.x + e[5]*h0[5]*c1.y + e[6]*h0[6]*c1.z + e[7]*h0[7]*c1.w;
                float yv = yp + __shfl_xor(yp, 1);
                if (!half) ybuf[i * XST + d] = yv;
            }
        }
    }
}

__global__ __launch_bounds__(256, 4) void k3_corr(
    const float* __restrict__ Wdt, const float* __restrict__ bias,
    const float* __restrict__ A_logs, const float* __restrict__ S_g,
    const float* __restrict__ xdbl, float* __restrict__ oy)
{
    const int blk = blockIdx.x;
    const int k = blk >> 7;
    const int c = blk & 127;
    if (c == 0) return;                 // chunk 0 has h0 = 0
    const int l0 = c * LC;
    const int t = threadIdx.x;

    __shared__ __align__(16) float sdbl[LC * SDST];
    __shared__ __align__(16) float ybuf[LC * XST];
    {
        const float4* g4 = (const float4*)(xdbl + (size_t)blk * XDBL_TILE);
        float4* s4 = (float4*)sdbl;
        for (int idx = t; idx < XDBL_TILE / 4; idx += 256) s4[idx] = g4[idx];
    }
    __syncthreads();

    const int d = t >> 1, half = t & 1, n0 = half * 8;
    float A8[8], A0;
    bool structured = load_A8(A_logs, k, d, n0, A8, A0);
    const float4* wp4 = (const float4*)(Wdt + (size_t)(k * DD + d) * RR);
    const float4 w0 = wp4[0], w1 = wp4[1];
    const float bz = bias[k * DD + d];

    float h0[8];
    {
        const float4* hp = (const float4*)(S_g + (((size_t)(k * NC + c) * DD + d) * NN + n0));
        float4 h40 = hp[0], h41 = hp[1];
        h0[0] = h40.x; h0[1] = h40.y; h0[2] = h40.z; h0[3] = h40.w;
        h0[4] = h41.x; h0[5] = h41.y; h0[6] = h41.z; h0[7] = h41.w;
    }

    if (structured)
        corr_body<true>(ybuf, sdbl, d, half, n0, A8, h0, w0, w1, bz);
    else
        corr_body<false>(ybuf, sdbl, d, half, n0, A8, h0, w0, w1, bz);

    // ---- transposed RMW of oy tile (intra-wave pair data) ----
    {
        float* base = oy + ((size_t)(k * DD + d)) * LL + l0 + half * 16;
        #pragma unroll
        for (int p = 0; p < 4; p++) {
            int j = p * 4;
            float4 v = *(float4*)(base + j);
            v.x += ybuf[(half * 16 + j + 0) * XST + d];
            v.y += ybuf[(half * 16 + j + 1) * XST + d];
            v.z += ybuf[(half * 16 + j + 2) * XST + d];
            v.w += ybuf[(half * 16 + j + 3) * XST + d];
            *(float4*)(base + j) = v;
        }
    }
}

// ---------------------------------------------------------------------------
// K4: restore + merge (reference's (D,L)-flat reshape semantics), float4.
// ---------------------------------------------------------------------------
__global__ __launch_bounds__(256) void k4_merge(
    const float* __restrict__ out_y, const float* __restrict__ mw,
    const float* __restrict__ mb, float* __restrict__ out)
{
    int idx4 = blockIdx.x * 256 + threadIdx.x;   // float4 index
    int dd4 = (idx4 & 31) * 4;
    int p = idx4 >> 5;
    int i3 = p & 15, i2 = (p >> 4) & 15, i1 = (p >> 8) & 15;

    float b = mb[0];
    float4 accv = make_float4(b, b, b, b);
    #pragma unroll
    for (int k = 0; k < 12; k++) {
        int a1 = i1, a2 = i2, a3 = i3;
        if (k & 1) { a1 = 15 - i1; a2 = 15 - i2; a3 = 15 - i3; }
        int j1, j2, j3;
        switch (k >> 1) {
            case 0:  j1 = a1; j2 = a2; j3 = a3; break;
            case 1:  j1 = a1; j2 = a3; j3 = a2; break;
            case 2:  j1 = a3; j2 = a2; j3 = a1; break;
            case 3:  j1 = a3; j2 = a1; j3 = a2; break;
            case 4:  j1 = a2; j2 = a1; j3 = a3; break;
            default: j1 = a2; j2 = a3; j3 = a1; break;
        }
        int jb = (j1 << 8) | (j2 << 4) | j3;
        float4 v = *(const float4*)(out_y + (size_t)k * (DD * LL) + (jb >> 5) * LL
                                    + ((jb & 31) << 7) + dd4);
        float w = mw[k];
        accv.x += w * v.x; accv.y += w * v.y;
        accv.z += w * v.z; accv.w += w * v.w;
    }
    *(float4*)(out + (size_t)p * DD + dd4) = accv;
}

extern "C" void kernel_launch(void* const* d_in, const int* in_sizes, int n_in,
                              void* d_out, int out_size, void* d_ws, size_t ws_size,
                              hipStream_t stream) {
    const float* x      = (const float*)d_in[0];
    const float* Wp     = (const float*)d_in[1];
    const float* Wdt    = (const float*)d_in[2];
    const float* bias   = (const float*)d_in[3];
    const float* A_logs = (const float*)d_in[4];
    const float* Ds     = (const float*)d_in[5];
    const float* mw     = (const float*)d_in[6];
    const float* mb     = (const float*)d_in[7];
    float* out = (float*)d_out;

    float* ws   = (float*)d_ws;
    float* S_g  = ws;                                 // K*NC*D*N = 1572864
    float* dts  = S_g + (size_t)KK * NC * DD * NN;    // K*NC*D   =   98304
    float* oy   = dts + (size_t)KK * NC * DD;         // K*D*L    = 6291456
    float* xdbl = oy + (size_t)KK * DD * LL;          // 1536*1408 = 2162688

    k1_proj_scanA<<<dim3(KK * NC), dim3(256), 0, stream>>>(
        x, Wp, Wdt, bias, A_logs, Ds, S_g, dts, oy, xdbl);
    k2_combine<<<dim3(KK * DD * NN / 32), dim3(256), 0, stream>>>(S_g, dts, A_logs);
    k3_corr<<<dim3(KK * NC), dim3(256), 0, stream>>>(Wdt, bias, A_logs, S_g, xdbl, oy);
    k4_merge<<<dim3(LL * DD / 1024), dim3(256), 0, stream>>>(oy, mw, mb, out);
}